// Round 16
// baseline (186.620 us; speedup 1.0000x reference)
//
#include <hip/hip_runtime.h>
#include <math.h>

#define NN 100000
#define EE 1600000
#define IND 128
#define D64 64    // HEADS*OUT_DIM

#define BSHIFT 8          // bucket = dst >> 8 (256 nodes per bucket)
#define NBUCK 391         // ceil(NN / 256)
#define P1_TILE 3072
#define NB_P1 521         // ceil(EE / P1_TILE)

#define QKV_BLOCKS 3125   // NN / 32 (2 waves x 16 nodes per 128-thr block)
#define WT_BLOCKS 96

typedef __attribute__((ext_vector_type(8))) short  short8;
typedef __attribute__((ext_vector_type(4))) float  f32x4;

__device__ __forceinline__ unsigned short bf16_rne(float v) {
    unsigned int u = __float_as_uint(v);
    return (unsigned short)((u + 0x7FFFu + ((u >> 16) & 1u)) >> 16);
}

// ---------------------------------------------------------------------------
// fusedA: blocks [0,96) = wtrans; blocks [96, 96+521) = p1a histogram.
// ---------------------------------------------------------------------------
__global__ __launch_bounds__(256) void fusedA_kernel(
    const float* __restrict__ Wq, const float* __restrict__ Wk,
    const float* __restrict__ Wv,
    unsigned short* __restrict__ wt_hi, unsigned short* __restrict__ wt_lo,
    const int* __restrict__ ei, int* __restrict__ hist)
{
    __shared__ int lh[NBUCK];
    const int t = threadIdx.x;

    if (blockIdx.x < WT_BLOCKS) {
        // ---- wtrans body ----
        int idx = blockIdx.x * 256 + t;           // 0..24575 == 192*128
        int col = idx >> 7, k = idx & 127;
        const float* W = (col < 64) ? Wq : (col < 128) ? Wk : Wv;
        float v = W[(size_t)k * D64 + (col & 63)];
        unsigned short h = bf16_rne(v);
        float hf = __uint_as_float((unsigned int)h << 16);
        unsigned short l = bf16_rne(v - hf);
        wt_hi[idx] = h;
        wt_lo[idx] = l;
        return;
    }

    // ---- p1a body ----
    const int pb = blockIdx.x - WT_BLOCKS;
    for (int b = t; b < NBUCK; b += 256) lh[b] = 0;
    __syncthreads();

    const int e0 = pb * P1_TILE;
#pragma unroll
    for (int j = 0; j < 12; ++j) {
        int e = e0 + j * 256 + t;
        if (e < EE) {
            int d = ei[EE + e];
            atomicAdd(&lh[d >> BSHIFT], 1);
        }
    }
    __syncthreads();
    for (int b = t; b < NBUCK; b += 256)
        hist[pb * NBUCK + b] = lh[b];
}

// ---------------------------------------------------------------------------
// hscanA: block b = bucket b. Unseeded exclusive scan of hist column
// (in place) + emits btot[b].
// ---------------------------------------------------------------------------
__global__ __launch_bounds__(256) void hscanA_kernel(int* __restrict__ hist,
                                                     int* __restrict__ btot)
{
    const int b = blockIdx.x;
    const int t = threadIdx.x;
    int L[3]; int s = 0;
#pragma unroll
    for (int j = 0; j < 3; ++j) {
        int blk = t * 3 + j;
        L[j] = (blk < NB_P1) ? hist[blk * NBUCK + b] : 0;
        s += L[j];
    }
    int lane = t & 63, w = t >> 6;
    int incl = s;
    for (int o = 1; o < 64; o <<= 1) {
        int v = __shfl_up(incl, o);
        if (lane >= o) incl += v;
    }
    __shared__ int wsum[4];
    if (lane == 63) wsum[w] = incl;
    __syncthreads();
    int wbase = 0;
#pragma unroll
    for (int i = 0; i < 4; ++i) if (i < w) wbase += wsum[i];
    int run = wbase + incl - s;          // unseeded exclusive offset
#pragma unroll
    for (int j = 0; j < 3; ++j) {
        int blk = t * 3 + j;
        if (blk < NB_P1) hist[blk * NBUCK + b] = run;
        run += L[j];
    }
    if (t == 0) btot[b] = wsum[0] + wsum[1] + wsum[2] + wsum[3];
}

// ---------------------------------------------------------------------------
// bscan: exclusive scan of 391 bucket totals -> bbase[0..391].
// ---------------------------------------------------------------------------
__global__ __launch_bounds__(256) void bscan_kernel(const int* __restrict__ btot,
                                                    int* __restrict__ bbase)
{
    const int t = threadIdx.x;
    int i0 = 2 * t, i1 = 2 * t + 1;
    int v0 = (i0 < NBUCK) ? btot[i0] : 0;
    int v1 = (i1 < NBUCK) ? btot[i1] : 0;
    int s = v0 + v1;
    int lane = t & 63, w = t >> 6;
    int incl = s;
    for (int o = 1; o < 64; o <<= 1) {
        int v = __shfl_up(incl, o);
        if (lane >= o) incl += v;
    }
    __shared__ int wsum[4];
    if (lane == 63) wsum[w] = incl;
    __syncthreads();
    int wbase = 0;
#pragma unroll
    for (int i = 0; i < 4; ++i) if (i < w) wbase += wsum[i];
    int excl = wbase + incl - s;
    if (i0 <= NBUCK) bbase[i0] = excl;
    if (i1 <= NBUCK) bbase[i1] = excl + v0;
}

// ---------------------------------------------------------------------------
// fusedB v3 (128 threads): blocks [0,521) = p1b (first, overlaps qkv);
// blocks [521, 521+3125) = qkv LDS-FREE: 2 waves x 16 nodes, A-frags loaded
// directly from global x (each row read once), B-frags streamed from L2-hot
// wt, hi/lo split in registers, K+V packed to one dword store per col.
// No LDS, no barriers in the qkv path.
// ---------------------------------------------------------------------------
__global__ __launch_bounds__(128) void fusedB_kernel(
    const float* __restrict__ x,
    const unsigned short* __restrict__ wt_hi,
    const unsigned short* __restrict__ wt_lo,
    const float* __restrict__ bq, const float* __restrict__ bk,
    const float* __restrict__ bv,
    float* __restrict__ Qo, unsigned int* __restrict__ KVb,
    const int* __restrict__ ei, const float* __restrict__ ea,
    const int* __restrict__ hist, const int* __restrict__ bbase,
    int2* __restrict__ staging)
{
    __shared__ int lr[NBUCK];
    const int t = threadIdx.x;

    if (blockIdx.x < NB_P1) {
        // ---- p1b body (128 threads, 24 edge iters) ----
        const int pb = blockIdx.x;
        for (int b = t; b < NBUCK; b += 128)
            lr[b] = hist[pb * NBUCK + b] + bbase[b];
        __syncthreads();

        const int e0 = pb * P1_TILE;
#pragma unroll
        for (int j = 0; j < 24; ++j) {
            int e = e0 + j * 128 + t;
            if (e < EE) {
                int s = ei[e];
                int d = ei[EE + e];
                int pos = atomicAdd(&lr[d >> BSHIFT], 1);
                staging[pos] = make_int2(s | ((d & 255) << 17), __float_as_int(ea[e]));
            }
        }
        return;
    }

    // ---- qkv body: wave-local, no LDS, no barriers ----
    const int qb   = blockIdx.x - NB_P1;       // 0..3124
    const int wave = t >> 6;                    // 0..1
    const int lane = t & 63;
    const int nb16 = qb * 32 + wave * 16;       // wave's 16-node base (exact)
    const int nr   = lane & 15;                 // node offset AND col offset
    const int q4   = lane >> 4;                 // k-quarter 0..3

    // upfront x loads: 4 kt x 8 floats at row (nb16+nr), k = kt*32 + q4*8
    const float* xr = x + (size_t)(nb16 + nr) * IND + q4 * 8;
    float4 xa[4][2];
#pragma unroll
    for (int kt = 0; kt < 4; ++kt) {
        xa[kt][0] = *(const float4*)(xr + kt * 32);
        xa[kt][1] = *(const float4*)(xr + kt * 32 + 4);
    }

    // per-thread biases (L2-hot scalars)
    float biasq[4], biask[4], biasv[4];
#pragma unroll
    for (int j = 0; j < 4; ++j) {
        biasq[j] = bq[j * 16 + nr];
        biask[j] = bk[j * 16 + nr];
        biasv[j] = bv[j * 16 + nr];
    }

    f32x4 acc[12];
#pragma unroll
    for (int c = 0; c < 12; ++c) acc[c] = (f32x4){0.f, 0.f, 0.f, 0.f};

#pragma unroll
    for (int kt = 0; kt < 4; ++kt) {
        // convert this kt's 8 x-floats to hi/lo bf16 fragments (in register)
        float vs[8] = { xa[kt][0].x, xa[kt][0].y, xa[kt][0].z, xa[kt][0].w,
                        xa[kt][1].x, xa[kt][1].y, xa[kt][1].z, xa[kt][1].w };
        short8 ah, al;
#pragma unroll
        for (int j = 0; j < 8; ++j) {
            unsigned short hb = bf16_rne(vs[j]);
            float hf = __uint_as_float((unsigned int)hb << 16);
            ah[j] = (short)hb;
            al[j] = (short)bf16_rne(vs[j] - hf);
        }
        // 12 col-tiles: stream B-frags from wt (L2-hot), 3 split MFMAs each
#pragma unroll
        for (int ct = 0; ct < 12; ++ct) {
            int col = ct * 16 + nr;
            int a = col * 128 + kt * 32 + q4 * 8;
            short8 bh = *(const short8*)&wt_hi[a];
            short8 bl = *(const short8*)&wt_lo[a];
            acc[ct] = __builtin_amdgcn_mfma_f32_16x16x32_bf16(ah, bh, acc[ct], 0, 0, 0);
            acc[ct] = __builtin_amdgcn_mfma_f32_16x16x32_bf16(ah, bl, acc[ct], 0, 0, 0);
            acc[ct] = __builtin_amdgcn_mfma_f32_16x16x32_bf16(al, bh, acc[ct], 0, 0, 0);
        }
    }

    // epilogue: Q fp32 dword stores; K+V packed to ONE dword store per col
#pragma unroll
    for (int j = 0; j < 4; ++j) {
#pragma unroll
        for (int reg = 0; reg < 4; ++reg) {
            int node = nb16 + q4 * 4 + reg;     // C/D row = (lane>>4)*4 + reg
            Qo[(size_t)node * D64 + j * 16 + nr] = acc[j][reg] + biasq[j];
        }
#pragma unroll
        for (int reg = 0; reg < 4; ++reg) {
            int node = nb16 + q4 * 4 + reg;
            float kv = acc[4 + j][reg] + biask[j];
            float vv = acc[8 + j][reg] + biasv[j];
            unsigned int pk = ((unsigned int)bf16_rne(kv) << 16) | bf16_rne(vv);
            KVb[(size_t)node * D64 + j * 16 + nr] = pk;
        }
    }
}

// ---------------------------------------------------------------------------
// p2: one block per bucket. Count per-node into LDS; 256-wide scan seeded
// at bbase[bucket] -> writes off[]; place records via LDS cursors.
// ---------------------------------------------------------------------------
__global__ __launch_bounds__(256) void p2_kernel(const int2* __restrict__ staging,
                                                 const int* __restrict__ bbase,
                                                 int* __restrict__ off,
                                                 int2* __restrict__ epack)
{
    const int bucket = blockIdx.x;
    const int t      = threadIdx.x;
    const int n0     = bucket << BSHIFT;
    const int sb     = bbase[bucket];
    const int se     = bbase[bucket + 1];

    __shared__ int lcnt[256];
    __shared__ int lcur[256];
    __shared__ int wsum[4];
    lcnt[t] = 0;
    __syncthreads();

    for (int r = sb + t; r < se; r += 256)
        atomicAdd(&lcnt[(staging[r].x >> 17) & 255], 1);
    __syncthreads();

    int cnt  = lcnt[t];
    int lane = t & 63, w = t >> 6;
    int incl = cnt;
    for (int o = 1; o < 64; o <<= 1) {
        int v = __shfl_up(incl, o);
        if (lane >= o) incl += v;
    }
    if (lane == 63) wsum[w] = incl;
    __syncthreads();
    int wbase = 0;
#pragma unroll
    for (int i = 0; i < 4; ++i) if (i < w) wbase += wsum[i];
    int ov = sb + wbase + incl - cnt;     // exclusive offset for node n0+t

    int node = n0 + t;
    if (node <= NN) off[node] = ov;
    lcur[t] = ov;
    __syncthreads();

    for (int r = sb + t; r < se; r += 256) {
        int2 rec = staging[r];
        int dl = (rec.x >> 17) & 255;
        int pos = atomicAdd(&lcur[dl], 1);
        epack[pos] = make_int2(rec.x & 0x1FFFF, rec.y);
    }
}

// ---------------------------------------------------------------------------
// Attention: one wave per dst node; lane = es*8 + h (8 edges x 8 heads).
// Unguarded full steps + one predicated tail; 32-bit byte addressing.
// ---------------------------------------------------------------------------
__global__ __launch_bounds__(256) void attn_kernel(
    const float* __restrict__ Q, const unsigned int* __restrict__ KVb,
    const int* __restrict__ off, const int2* __restrict__ epack,
    const float* __restrict__ We, const float* __restrict__ be,
    float* __restrict__ out)
{
    const int lane = threadIdx.x & 63;
    const int node = blockIdx.x * 4 + (threadIdx.x >> 6);   // grid exact: < NN

    const int h  = lane & 7;    // head owned by this lane
    const int es = lane >> 3;   // edge slot 0..7

    // ---- hoist: fold Q, We, be, 1/sqrt(8) into per-d score coefficients ----
    float wq[8], bq[8];
    {
        const float4* qp = (const float4*)&Q[(size_t)node * D64 + h * 8];
        float4 q0 = qp[0], q1 = qp[1];
        const float4* wp = (const float4*)&We[h * 8];
        float4 w0 = wp[0], w1 = wp[1];
        const float4* bp = (const float4*)&be[h * 8];
        float4 b0 = bp[0], b1 = bp[1];
        const float rs = 0.35355339059327373f;
        float qs[8] = { q0.x, q0.y, q0.z, q0.w, q1.x, q1.y, q1.z, q1.w };
        float ws[8] = { w0.x, w0.y, w0.z, w0.w, w1.x, w1.y, w1.z, w1.w };
        float bs[8] = { b0.x, b0.y, b0.z, b0.w, b1.x, b1.y, b1.z, b1.w };
#pragma unroll
        for (int d = 0; d < 8; ++d) {
            float qr = qs[d] * rs;
            wq[d] = ws[d] * qr;
            bq[d] = bs[d] * qr;
        }
    }

    const int i0 = off[node];
    const int i1 = off[node + 1];

    float acc[8];
#pragma unroll
    for (int d = 0; d < 8; ++d) acc[d] = 0.f;
    float z = 0.f;

    int i = i0;
    // ---- full steps: no predication anywhere ----
#pragma unroll 2
    for (; i + 8 <= i1; i += 8) {
        int2 rec = epack[i + es];
        unsigned int bo = ((unsigned int)rec.x << 6) + (h << 3);
        float attr = __int_as_float(rec.y);

        uint4 wA = *(const uint4*)(KVb + bo);
        uint4 wB = *(const uint4*)(KVb + bo + 4);
        unsigned int wv[8] = { wA.x, wA.y, wA.z, wA.w, wB.x, wB.y, wB.z, wB.w };

        float tt = 0.f;
#pragma unroll
        for (int d = 0; d < 8; ++d) {
            float s  = fmaf(attr, wq[d], bq[d]);
            float kf = __uint_as_float(wv[d] & 0xFFFF0000u);
            tt = fmaf(kf, s, tt);
        }
        tt = fminf(fmaxf(tt, -5.f), 5.f);
        float sc = __expf(tt);

#pragma unroll
        for (int d = 0; d < 8; ++d) {
            float vf = __uint_as_float(wv[d] << 16);
            acc[d] = fmaf(vf, sc, acc[d]);
        }
        z += sc;
    }

    // ---- tail: one predicated step covers remaining 0..7 edges ----
    if (i < i1) {
        int  idx   = i + es;
        bool valid = idx < i1;
        int2 rec   = epack[valid ? idx : i0];
        unsigned int bo = ((unsigned int)rec.x << 6) + (h << 3);
        float attr = __int_as_float(rec.y);

        uint4 wA = *(const uint4*)(KVb + bo);
        uint4 wB = *(const uint4*)(KVb + bo + 4);
        unsigned int wv[8] = { wA.x, wA.y, wA.z, wA.w, wB.x, wB.y, wB.z, wB.w };

        float tt = 0.f;
#pragma unroll
        for (int d = 0; d < 8; ++d) {
            float s  = fmaf(attr, wq[d], bq[d]);
            float kf = __uint_as_float(wv[d] & 0xFFFF0000u);
            tt = fmaf(kf, s, tt);
        }
        tt = fminf(fmaxf(tt, -5.f), 5.f);
        float sc = __expf(tt);
        sc = valid ? sc : 0.f;

#pragma unroll
        for (int d = 0; d < 8; ++d) {
            float vf = __uint_as_float(wv[d] << 16);
            acc[d] = fmaf(vf, sc, acc[d]);
        }
        z += sc;
    }

    // ---- butterfly reduce across edge slots (lane bits 3..5) ----
#pragma unroll
    for (int m = 8; m <= 32; m <<= 1) {
#pragma unroll
        for (int d = 0; d < 8; ++d) acc[d] += __shfl_xor(acc[d], m);
        z += __shfl_xor(z, m);
    }

    // ---- lane writes out[node][h*8 + es] = acc[es] / (z + eps) ----
    float val = acc[0];
#pragma unroll
    for (int j = 1; j < 8; ++j)
        val = (es == j) ? acc[j] : val;

    out[(size_t)node * D64 + h * 8 + es] = val / (z + 1e-6f);
}

// ---------------------------------------------------------------------------
// Host launcher
// ---------------------------------------------------------------------------
static inline size_t align256(size_t v) { return (v + 255) & ~(size_t)255; }

extern "C" void kernel_launch(void* const* d_in, const int* in_sizes, int n_in,
                              void* d_out, int out_size, void* d_ws, size_t ws_size,
                              hipStream_t stream)
{
    const float* x  = (const float*)d_in[0];
    const float* ea = (const float*)d_in[1];
    const int*   ei = (const int*)  d_in[2];   // [2][EE]: row0=src, row1=dst
    const float* Wq = (const float*)d_in[3];
    const float* bq = (const float*)d_in[4];
    const float* Wk = (const float*)d_in[5];
    const float* bk = (const float*)d_in[6];
    const float* We = (const float*)d_in[7];
    const float* be = (const float*)d_in[8];
    const float* Wv = (const float*)d_in[9];
    const float* bv = (const float*)d_in[10];
    float* out = (float*)d_out;

    char* ws = (char*)d_ws;
    size_t o = 0;
    float*          Q       = (float*)(ws + o);          o += align256((size_t)NN * D64 * 4);
    unsigned int*   KVb     = (unsigned int*)(ws + o);   o += align256((size_t)NN * D64 * 4);
    int*            off     = (int*)(ws + o);            o += align256((size_t)(NN + 1) * 4);
    unsigned short* wt_hi   = (unsigned short*)(ws + o); o += align256((size_t)192 * 128 * 2);
    unsigned short* wt_lo   = (unsigned short*)(ws + o); o += align256((size_t)192 * 128 * 2);
    int*            hist    = (int*)(ws + o);            o += align256((size_t)NB_P1 * NBUCK * 4);
    int*            btot    = (int*)(ws + o);            o += align256((size_t)NBUCK * 4);
    int*            bbase   = (int*)(ws + o);            o += align256((size_t)(NBUCK + 1) * 4);
    int2*           staging = (int2*)(ws + o);           o += align256((size_t)EE * 8);
    int2*           epack   = (int2*)(ws + o);           o += align256((size_t)EE * 8);
    (void)ws_size; (void)out_size; (void)in_sizes; (void)n_in;

    fusedA_kernel<<<WT_BLOCKS + NB_P1, 256, 0, stream>>>(Wq, Wk, Wv, wt_hi, wt_lo, ei, hist);
    hscanA_kernel<<<NBUCK, 256, 0, stream>>>(hist, btot);
    bscan_kernel<<<1, 256, 0, stream>>>(btot, bbase);
    fusedB_kernel<<<NB_P1 + QKV_BLOCKS, 128, 0, stream>>>(x, wt_hi, wt_lo, bq, bk, bv,
                                                          Q, KVb, ei, ea, hist, bbase, staging);
    p2_kernel<<<NBUCK, 256, 0, stream>>>(staging, bbase, off, epack);
    attn_kernel<<<NN / 4, 256, 0, stream>>>(Q, KVb, off, epack, We, be, out);
}

// Round 17
// 156.591 us; speedup vs baseline: 1.1918x; 1.1918x over previous
//
#include <hip/hip_runtime.h>
#include <math.h>

#define NN 100000
#define EE 1600000
#define IND 128
#define D64 64    // HEADS*OUT_DIM

#define BSHIFT 8          // bucket = dst >> 8 (256 nodes per bucket)
#define NBUCK 391         // ceil(NN / 256)
#define P1_TILE 3072
#define NB_P1 521         // ceil(EE / P1_TILE)

#define QKV_BLOCKS 3125   // NN / 32
#define WT_BLOCKS 96

typedef __attribute__((ext_vector_type(8))) short  short8;
typedef __attribute__((ext_vector_type(4))) float  f32x4;

__device__ __forceinline__ unsigned short bf16_rne(float v) {
    unsigned int u = __float_as_uint(v);
    return (unsigned short)((u + 0x7FFFu + ((u >> 16) & 1u)) >> 16);
}

// ---------------------------------------------------------------------------
// fusedA: blocks [0,96) = wtrans; blocks [96, 96+521) = p1a histogram.
// ---------------------------------------------------------------------------
__global__ __launch_bounds__(256) void fusedA_kernel(
    const float* __restrict__ Wq, const float* __restrict__ Wk,
    const float* __restrict__ Wv,
    unsigned short* __restrict__ wt_hi, unsigned short* __restrict__ wt_lo,
    const int* __restrict__ ei, int* __restrict__ hist)
{
    __shared__ int lh[NBUCK];
    const int t = threadIdx.x;

    if (blockIdx.x < WT_BLOCKS) {
        // ---- wtrans body ----
        int idx = blockIdx.x * 256 + t;           // 0..24575 == 192*128
        int col = idx >> 7, k = idx & 127;
        const float* W = (col < 64) ? Wq : (col < 128) ? Wk : Wv;
        float v = W[(size_t)k * D64 + (col & 63)];
        unsigned short h = bf16_rne(v);
        float hf = __uint_as_float((unsigned int)h << 16);
        unsigned short l = bf16_rne(v - hf);
        wt_hi[idx] = h;
        wt_lo[idx] = l;
        return;
    }

    // ---- p1a body ----
    const int pb = blockIdx.x - WT_BLOCKS;
    for (int b = t; b < NBUCK; b += 256) lh[b] = 0;
    __syncthreads();

    const int e0 = pb * P1_TILE;
#pragma unroll
    for (int j = 0; j < 12; ++j) {
        int e = e0 + j * 256 + t;
        if (e < EE) {
            int d = ei[EE + e];
            atomicAdd(&lh[d >> BSHIFT], 1);
        }
    }
    __syncthreads();
    for (int b = t; b < NBUCK; b += 256)
        hist[pb * NBUCK + b] = lh[b];
}

// ---------------------------------------------------------------------------
// hscanA: block b = bucket b. Unseeded exclusive scan of hist column
// (in place) + emits btot[b].
// ---------------------------------------------------------------------------
__global__ __launch_bounds__(256) void hscanA_kernel(int* __restrict__ hist,
                                                     int* __restrict__ btot)
{
    const int b = blockIdx.x;
    const int t = threadIdx.x;
    int L[3]; int s = 0;
#pragma unroll
    for (int j = 0; j < 3; ++j) {
        int blk = t * 3 + j;
        L[j] = (blk < NB_P1) ? hist[blk * NBUCK + b] : 0;
        s += L[j];
    }
    int lane = t & 63, w = t >> 6;
    int incl = s;
    for (int o = 1; o < 64; o <<= 1) {
        int v = __shfl_up(incl, o);
        if (lane >= o) incl += v;
    }
    __shared__ int wsum[4];
    if (lane == 63) wsum[w] = incl;
    __syncthreads();
    int wbase = 0;
#pragma unroll
    for (int i = 0; i < 4; ++i) if (i < w) wbase += wsum[i];
    int run = wbase + incl - s;          // unseeded exclusive offset
#pragma unroll
    for (int j = 0; j < 3; ++j) {
        int blk = t * 3 + j;
        if (blk < NB_P1) hist[blk * NBUCK + b] = run;
        run += L[j];
    }
    if (t == 0) btot[b] = wsum[0] + wsum[1] + wsum[2] + wsum[3];
}

// ---------------------------------------------------------------------------
// bscan: exclusive scan of 391 bucket totals -> bbase[0..391].
// ---------------------------------------------------------------------------
__global__ __launch_bounds__(256) void bscan_kernel(const int* __restrict__ btot,
                                                    int* __restrict__ bbase)
{
    const int t = threadIdx.x;
    int i0 = 2 * t, i1 = 2 * t + 1;
    int v0 = (i0 < NBUCK) ? btot[i0] : 0;
    int v1 = (i1 < NBUCK) ? btot[i1] : 0;
    int s = v0 + v1;
    int lane = t & 63, w = t >> 6;
    int incl = s;
    for (int o = 1; o < 64; o <<= 1) {
        int v = __shfl_up(incl, o);
        if (lane >= o) incl += v;
    }
    __shared__ int wsum[4];
    if (lane == 63) wsum[w] = incl;
    __syncthreads();
    int wbase = 0;
#pragma unroll
    for (int i = 0; i < 4; ++i) if (i < w) wbase += wsum[i];
    int excl = wbase + incl - s;
    if (i0 <= NBUCK) bbase[i0] = excl;
    if (i1 <= NBUCK) bbase[i1] = excl + v0;
}

// ---------------------------------------------------------------------------
// fusedB (round-14 structure, p1b FIRST): blocks [0,521) = p1b scatter
// (overlaps qkv); blocks [521, 521+3125) = qkv single-tile LDS-staged,
// XP=132, B-frags streamed per kt from L2-hot wt.
// ---------------------------------------------------------------------------
#define XP 132   // padded k-stride (ushort) for LDS x tiles

__global__ __launch_bounds__(256) void fusedB_kernel(
    const float* __restrict__ x,
    const unsigned short* __restrict__ wt_hi,
    const unsigned short* __restrict__ wt_lo,
    const float* __restrict__ bq, const float* __restrict__ bk,
    const float* __restrict__ bv,
    float* __restrict__ Qo, unsigned int* __restrict__ KVb,
    const int* __restrict__ ei, const float* __restrict__ ea,
    const int* __restrict__ hist, const int* __restrict__ bbase,
    int2* __restrict__ staging)
{
    __shared__ __align__(16) char smem[2 * 32 * XP * 2];   // 16896 B union

    const int t = threadIdx.x;

    if (blockIdx.x < NB_P1) {
        // ---- p1b body (first: overlaps qkv compute) ----
        int* lr = (int*)smem;
        const int pb = blockIdx.x;
        for (int b = t; b < NBUCK; b += 256)
            lr[b] = hist[pb * NBUCK + b] + bbase[b];
        __syncthreads();

        const int e0 = pb * P1_TILE;
#pragma unroll
        for (int j = 0; j < 12; ++j) {
            int e = e0 + j * 256 + t;
            if (e < EE) {
                int s = ei[e];
                int d = ei[EE + e];
                int pos = atomicAdd(&lr[d >> BSHIFT], 1);
                staging[pos] = make_int2(s | ((d & 255) << 17), __float_as_int(ea[e]));
            }
        }
        return;
    }

    // ---- qkv body ----
    unsigned short* xhi = (unsigned short*)smem;             // 32*XP ushorts
    unsigned short* xlo = (unsigned short*)(smem + 32 * XP * 2);

    const int qb   = blockIdx.x - NB_P1;     // 0..3124
    const int wave = t >> 6;
    const int lane = t & 63;
    const int nb   = qb * 32;                // 3125 * 32 = 100000 exact

    // stage x tile 32x128 fp32 -> hi/lo bf16 in LDS (16 floats/thread)
    {
        const int row = t >> 3;          // 0..31
        const int c   = t & 7;           // 16-float chunk
        const float* xr = x + (size_t)(nb + row) * IND + c * 16;
        float4 a0 = *(const float4*)(xr);
        float4 a1 = *(const float4*)(xr + 4);
        float4 a2 = *(const float4*)(xr + 8);
        float4 a3 = *(const float4*)(xr + 12);
        float vs[16] = { a0.x, a0.y, a0.z, a0.w, a1.x, a1.y, a1.z, a1.w,
                         a2.x, a2.y, a2.z, a2.w, a3.x, a3.y, a3.z, a3.w };
        short8 h0, h1, l0, l1;
#pragma unroll
        for (int j = 0; j < 8; ++j) {
            unsigned short hb = bf16_rne(vs[j]);
            float hf = __uint_as_float((unsigned int)hb << 16);
            h0[j] = (short)hb;
            l0[j] = (short)bf16_rne(vs[j] - hf);
        }
#pragma unroll
        for (int j = 0; j < 8; ++j) {
            unsigned short hb = bf16_rne(vs[8 + j]);
            float hf = __uint_as_float((unsigned int)hb << 16);
            h1[j] = (short)hb;
            l1[j] = (short)bf16_rne(vs[8 + j] - hf);
        }
        int o0 = row * XP + c * 16;
        *(short8*)&xhi[o0]     = h0;
        *(short8*)&xhi[o0 + 8] = h1;
        *(short8*)&xlo[o0]     = l0;
        *(short8*)&xlo[o0 + 8] = l1;
    }
    __syncthreads();

    const int wcol0 = wave * 48;

    f32x4 acc[2][3];
#pragma unroll
    for (int rt = 0; rt < 2; ++rt)
#pragma unroll
        for (int ct = 0; ct < 3; ++ct)
            acc[rt][ct] = (f32x4){0.f, 0.f, 0.f, 0.f};

#pragma unroll
    for (int kt = 0; kt < 4; ++kt) {
        // stream B-fragments for this kt (L2-hot, 6 x dwordx4)
        short8 bh[3], bl[3];
#pragma unroll
        for (int ct = 0; ct < 3; ++ct) {
            int col = wcol0 + ct * 16 + (lane & 15);
            int a = col * 128 + kt * 32 + (lane >> 4) * 8;
            bh[ct] = *(const short8*)&wt_hi[a];
            bl[ct] = *(const short8*)&wt_lo[a];
        }
        // A-fragments from LDS (4 x ds_read_b128)
        short8 ah[2], al[2];
#pragma unroll
        for (int rt = 0; rt < 2; ++rt) {
            int o2 = (rt * 16 + (lane & 15)) * XP + kt * 32 + (lane >> 4) * 8;
            ah[rt] = *(const short8*)&xhi[o2];
            al[rt] = *(const short8*)&xlo[o2];
        }
#pragma unroll
        for (int rt = 0; rt < 2; ++rt) {
#pragma unroll
            for (int ct = 0; ct < 3; ++ct) {
                acc[rt][ct] = __builtin_amdgcn_mfma_f32_16x16x32_bf16(
                    ah[rt], bh[ct], acc[rt][ct], 0, 0, 0);
                acc[rt][ct] = __builtin_amdgcn_mfma_f32_16x16x32_bf16(
                    ah[rt], bl[ct], acc[rt][ct], 0, 0, 0);
                acc[rt][ct] = __builtin_amdgcn_mfma_f32_16x16x32_bf16(
                    al[rt], bh[ct], acc[rt][ct], 0, 0, 0);
            }
        }
    }

    // epilogue: bias + store. Q fp32; K -> hi ushort, V -> lo ushort
#pragma unroll
    for (int ct = 0; ct < 3; ++ct) {
        int colbase = wcol0 + ct * 16;
        int m  = colbase >> 6;                 // wave-uniform: 0=Q,1=K,2=V
        int lc = (colbase & 63) + (lane & 15);
        const float* bp = (m == 0) ? bq : (m == 1) ? bk : bv;
        float bias = bp[lc];
#pragma unroll
        for (int rt = 0; rt < 2; ++rt) {
#pragma unroll
            for (int reg = 0; reg < 4; ++reg) {
                int node = nb + rt * 16 + (lane >> 4) * 4 + reg;
                float val = acc[rt][ct][reg] + bias;
                size_t idx = (size_t)node * D64 + lc;
                if (m == 0) {
                    Qo[idx] = val;
                } else {
                    // little-endian: ushort[0]=lo(V), ushort[1]=hi(K)
                    ((unsigned short*)KVb)[idx * 2 + (m == 1 ? 1 : 0)] = bf16_rne(val);
                }
            }
        }
    }
}

// ---------------------------------------------------------------------------
// p2: one block per bucket. Count per-node into LDS; 256-wide scan seeded
// at bbase[bucket] -> writes off[]; place records via LDS cursors.
// ---------------------------------------------------------------------------
__global__ __launch_bounds__(256) void p2_kernel(const int2* __restrict__ staging,
                                                 const int* __restrict__ bbase,
                                                 int* __restrict__ off,
                                                 int2* __restrict__ epack)
{
    const int bucket = blockIdx.x;
    const int t      = threadIdx.x;
    const int n0     = bucket << BSHIFT;
    const int sb     = bbase[bucket];
    const int se     = bbase[bucket + 1];

    __shared__ int lcnt[256];
    __shared__ int lcur[256];
    __shared__ int wsum[4];
    lcnt[t] = 0;
    __syncthreads();

    for (int r = sb + t; r < se; r += 256)
        atomicAdd(&lcnt[(staging[r].x >> 17) & 255], 1);
    __syncthreads();

    int cnt  = lcnt[t];
    int lane = t & 63, w = t >> 6;
    int incl = cnt;
    for (int o = 1; o < 64; o <<= 1) {
        int v = __shfl_up(incl, o);
        if (lane >= o) incl += v;
    }
    if (lane == 63) wsum[w] = incl;
    __syncthreads();
    int wbase = 0;
#pragma unroll
    for (int i = 0; i < 4; ++i) if (i < w) wbase += wsum[i];
    int ov = sb + wbase + incl - cnt;     // exclusive offset for node n0+t

    int node = n0 + t;
    if (node <= NN) off[node] = ov;
    lcur[t] = ov;
    __syncthreads();

    for (int r = sb + t; r < se; r += 256) {
        int2 rec = staging[r];
        int dl = (rec.x >> 17) & 255;
        int pos = atomicAdd(&lcur[dl], 1);
        epack[pos] = make_int2(rec.x & 0x1FFFF, rec.y);
    }
}

// ---------------------------------------------------------------------------
// Attention: one wave per dst node; lane = es*8 + h (8 edges x 8 heads).
// Unguarded full steps + one predicated tail; 32-bit byte addressing.
// ---------------------------------------------------------------------------
__global__ __launch_bounds__(256) void attn_kernel(
    const float* __restrict__ Q, const unsigned int* __restrict__ KVb,
    const int* __restrict__ off, const int2* __restrict__ epack,
    const float* __restrict__ We, const float* __restrict__ be,
    float* __restrict__ out)
{
    const int lane = threadIdx.x & 63;
    const int node = blockIdx.x * 4 + (threadIdx.x >> 6);   // grid exact: < NN

    const int h  = lane & 7;    // head owned by this lane
    const int es = lane >> 3;   // edge slot 0..7

    // ---- hoist: fold Q, We, be, 1/sqrt(8) into per-d score coefficients ----
    float wq[8], bq[8];
    {
        const float4* qp = (const float4*)&Q[(size_t)node * D64 + h * 8];
        float4 q0 = qp[0], q1 = qp[1];
        const float4* wp = (const float4*)&We[h * 8];
        float4 w0 = wp[0], w1 = wp[1];
        const float4* bp = (const float4*)&be[h * 8];
        float4 b0 = bp[0], b1 = bp[1];
        const float rs = 0.35355339059327373f;
        float qs[8] = { q0.x, q0.y, q0.z, q0.w, q1.x, q1.y, q1.z, q1.w };
        float ws[8] = { w0.x, w0.y, w0.z, w0.w, w1.x, w1.y, w1.z, w1.w };
        float bs[8] = { b0.x, b0.y, b0.z, b0.w, b1.x, b1.y, b1.z, b1.w };
#pragma unroll
        for (int d = 0; d < 8; ++d) {
            float qr = qs[d] * rs;
            wq[d] = ws[d] * qr;
            bq[d] = bs[d] * qr;
        }
    }

    const int i0 = off[node];
    const int i1 = off[node + 1];

    float acc[8];
#pragma unroll
    for (int d = 0; d < 8; ++d) acc[d] = 0.f;
    float z = 0.f;

    int i = i0;
    // ---- full steps: no predication anywhere ----
#pragma unroll 2
    for (; i + 8 <= i1; i += 8) {
        int2 rec = epack[i + es];
        unsigned int bo = ((unsigned int)rec.x << 6) + (h << 3);
        float attr = __int_as_float(rec.y);

        uint4 wA = *(const uint4*)(KVb + bo);
        uint4 wB = *(const uint4*)(KVb + bo + 4);
        unsigned int wv[8] = { wA.x, wA.y, wA.z, wA.w, wB.x, wB.y, wB.z, wB.w };

        float tt = 0.f;
#pragma unroll
        for (int d = 0; d < 8; ++d) {
            float s  = fmaf(attr, wq[d], bq[d]);
            float kf = __uint_as_float(wv[d] & 0xFFFF0000u);
            tt = fmaf(kf, s, tt);
        }
        tt = fminf(fmaxf(tt, -5.f), 5.f);
        float sc = __expf(tt);

#pragma unroll
        for (int d = 0; d < 8; ++d) {
            float vf = __uint_as_float(wv[d] << 16);
            acc[d] = fmaf(vf, sc, acc[d]);
        }
        z += sc;
    }

    // ---- tail: one predicated step covers remaining 0..7 edges ----
    if (i < i1) {
        int  idx   = i + es;
        bool valid = idx < i1;
        int2 rec   = epack[valid ? idx : i0];
        unsigned int bo = ((unsigned int)rec.x << 6) + (h << 3);
        float attr = __int_as_float(rec.y);

        uint4 wA = *(const uint4*)(KVb + bo);
        uint4 wB = *(const uint4*)(KVb + bo + 4);
        unsigned int wv[8] = { wA.x, wA.y, wA.z, wA.w, wB.x, wB.y, wB.z, wB.w };

        float tt = 0.f;
#pragma unroll
        for (int d = 0; d < 8; ++d) {
            float s  = fmaf(attr, wq[d], bq[d]);
            float kf = __uint_as_float(wv[d] & 0xFFFF0000u);
            tt = fmaf(kf, s, tt);
        }
        tt = fminf(fmaxf(tt, -5.f), 5.f);
        float sc = __expf(tt);
        sc = valid ? sc : 0.f;

#pragma unroll
        for (int d = 0; d < 8; ++d) {
            float vf = __uint_as_float(wv[d] << 16);
            acc[d] = fmaf(vf, sc, acc[d]);
        }
        z += sc;
    }

    // ---- butterfly reduce across edge slots (lane bits 3..5) ----
#pragma unroll
    for (int m = 8; m <= 32; m <<= 1) {
#pragma unroll
        for (int d = 0; d < 8; ++d) acc[d] += __shfl_xor(acc[d], m);
        z += __shfl_xor(z, m);
    }

    // ---- lane writes out[node][h*8 + es] = acc[es] / (z + eps) ----
    float val = acc[0];
#pragma unroll
    for (int j = 1; j < 8; ++j)
        val = (es == j) ? acc[j] : val;

    out[(size_t)node * D64 + h * 8 + es] = val / (z + 1e-6f);
}

// ---------------------------------------------------------------------------
// Host launcher
// ---------------------------------------------------------------------------
static inline size_t align256(size_t v) { return (v + 255) & ~(size_t)255; }

extern "C" void kernel_launch(void* const* d_in, const int* in_sizes, int n_in,
                              void* d_out, int out_size, void* d_ws, size_t ws_size,
                              hipStream_t stream)
{
    const float* x  = (const float*)d_in[0];
    const float* ea = (const float*)d_in[1];
    const int*   ei = (const int*)  d_in[2];   // [2][EE]: row0=src, row1=dst
    const float* Wq = (const float*)d_in[3];
    const float* bq = (const float*)d_in[4];
    const float* Wk = (const float*)d_in[5];
    const float* bk = (const float*)d_in[6];
    const float* We = (const float*)d_in[7];
    const float* be = (const float*)d_in[8];
    const float* Wv = (const float*)d_in[9];
    const float* bv = (const float*)d_in[10];
    float* out = (float*)d_out;

    char* ws = (char*)d_ws;
    size_t o = 0;
    float*          Q       = (float*)(ws + o);          o += align256((size_t)NN * D64 * 4);
    unsigned int*   KVb     = (unsigned int*)(ws + o);   o += align256((size_t)NN * D64 * 4);
    int*            off     = (int*)(ws + o);            o += align256((size_t)(NN + 1) * 4);
    unsigned short* wt_hi   = (unsigned short*)(ws + o); o += align256((size_t)192 * 128 * 2);
    unsigned short* wt_lo   = (unsigned short*)(ws + o); o += align256((size_t)192 * 128 * 2);
    int*            hist    = (int*)(ws + o);            o += align256((size_t)NB_P1 * NBUCK * 4);
    int*            btot    = (int*)(ws + o);            o += align256((size_t)NBUCK * 4);
    int*            bbase   = (int*)(ws + o);            o += align256((size_t)(NBUCK + 1) * 4);
    int2*           staging = (int2*)(ws + o);           o += align256((size_t)EE * 8);
    int2*           epack   = (int2*)(ws + o);           o += align256((size_t)EE * 8);
    (void)ws_size; (void)out_size; (void)in_sizes; (void)n_in;

    fusedA_kernel<<<WT_BLOCKS + NB_P1, 256, 0, stream>>>(Wq, Wk, Wv, wt_hi, wt_lo, ei, hist);
    hscanA_kernel<<<NBUCK, 256, 0, stream>>>(hist, btot);
    bscan_kernel<<<1, 256, 0, stream>>>(btot, bbase);
    fusedB_kernel<<<NB_P1 + QKV_BLOCKS, 256, 0, stream>>>(x, wt_hi, wt_lo, bq, bk, bv,
                                                          Q, KVb, ei, ea, hist, bbase, staging);
    p2_kernel<<<NBUCK, 256, 0, stream>>>(staging, bbase, off, epack);
    attn_kernel<<<NN / 4, 256, 0, stream>>>(Q, KVb, off, epack, We, be, out);
}

// Round 18
// 144.870 us; speedup vs baseline: 1.2882x; 1.0809x over previous
//
#include <hip/hip_runtime.h>
#include <math.h>

#define NN 100000
#define EE 1600000
#define IND 128
#define D64 64    // HEADS*OUT_DIM

#define BSHIFT 8          // bucket = dst >> 8 (256 nodes per bucket)
#define NBUCK 391         // ceil(NN / 256)
#define P1_TILE 3072
#define NB_P1 521         // ceil(EE / P1_TILE)

#define QKV_BLOCKS 3125   // NN / 32
#define WT_BLOCKS 96

typedef __attribute__((ext_vector_type(8))) short  short8;
typedef __attribute__((ext_vector_type(4))) float  f32x4;

__device__ __forceinline__ unsigned short bf16_rne(float v) {
    unsigned int u = __float_as_uint(v);
    return (unsigned short)((u + 0x7FFFu + ((u >> 16) & 1u)) >> 16);
}

// ---------------------------------------------------------------------------
// fusedA: blocks [0,96) = wtrans -> FRAGMENT-PACKED wt layout:
//   wt[((ct*4+kt)*64 + lane)*8 + j] = W[kt*32+(lane>>4)*8+j][ct*16+(lane&15)]
// so each MFMA B-fragment is one coalesced 1KB wave-load.
// blocks [96, 96+521) = p1a histogram.
// ---------------------------------------------------------------------------
__global__ __launch_bounds__(256) void fusedA_kernel(
    const float* __restrict__ Wq, const float* __restrict__ Wk,
    const float* __restrict__ Wv,
    unsigned short* __restrict__ wt_hi, unsigned short* __restrict__ wt_lo,
    const int* __restrict__ ei, int* __restrict__ hist)
{
    __shared__ int lh[NBUCK];
    const int t = threadIdx.x;

    if (blockIdx.x < WT_BLOCKS) {
        // ---- wtrans body (fragment-packed) ----
        int idx = blockIdx.x * 256 + t;           // 0..24575 == 192*128
        int j    = idx & 7;
        int lane = (idx >> 3) & 63;
        int ktct = idx >> 9;                      // 0..47
        int kt   = ktct & 3;
        int ct   = ktct >> 2;                     // 0..11
        int col  = ct * 16 + (lane & 15);
        int k    = kt * 32 + (lane >> 4) * 8 + j;
        const float* W = (col < 64) ? Wq : (col < 128) ? Wk : Wv;
        float v = W[(size_t)k * D64 + (col & 63)];
        unsigned short h = bf16_rne(v);
        float hf = __uint_as_float((unsigned int)h << 16);
        unsigned short l = bf16_rne(v - hf);
        wt_hi[idx] = h;
        wt_lo[idx] = l;
        return;
    }

    // ---- p1a body ----
    const int pb = blockIdx.x - WT_BLOCKS;
    for (int b = t; b < NBUCK; b += 256) lh[b] = 0;
    __syncthreads();

    const int e0 = pb * P1_TILE;
#pragma unroll
    for (int j = 0; j < 12; ++j) {
        int e = e0 + j * 256 + t;
        if (e < EE) {
            int d = ei[EE + e];
            atomicAdd(&lh[d >> BSHIFT], 1);
        }
    }
    __syncthreads();
    for (int b = t; b < NBUCK; b += 256)
        hist[pb * NBUCK + b] = lh[b];
}

// ---------------------------------------------------------------------------
// hscanA: block b = bucket b. Unseeded exclusive scan of hist column
// (in place) + emits btot[b].
// ---------------------------------------------------------------------------
__global__ __launch_bounds__(256) void hscanA_kernel(int* __restrict__ hist,
                                                     int* __restrict__ btot)
{
    const int b = blockIdx.x;
    const int t = threadIdx.x;
    int L[3]; int s = 0;
#pragma unroll
    for (int j = 0; j < 3; ++j) {
        int blk = t * 3 + j;
        L[j] = (blk < NB_P1) ? hist[blk * NBUCK + b] : 0;
        s += L[j];
    }
    int lane = t & 63, w = t >> 6;
    int incl = s;
    for (int o = 1; o < 64; o <<= 1) {
        int v = __shfl_up(incl, o);
        if (lane >= o) incl += v;
    }
    __shared__ int wsum[4];
    if (lane == 63) wsum[w] = incl;
    __syncthreads();
    int wbase = 0;
#pragma unroll
    for (int i = 0; i < 4; ++i) if (i < w) wbase += wsum[i];
    int run = wbase + incl - s;          // unseeded exclusive offset
#pragma unroll
    for (int j = 0; j < 3; ++j) {
        int blk = t * 3 + j;
        if (blk < NB_P1) hist[blk * NBUCK + b] = run;
        run += L[j];
    }
    if (t == 0) btot[b] = wsum[0] + wsum[1] + wsum[2] + wsum[3];
}

// ---------------------------------------------------------------------------
// bscan: exclusive scan of 391 bucket totals -> bbase[0..391].
// ---------------------------------------------------------------------------
__global__ __launch_bounds__(256) void bscan_kernel(const int* __restrict__ btot,
                                                    int* __restrict__ bbase)
{
    const int t = threadIdx.x;
    int i0 = 2 * t, i1 = 2 * t + 1;
    int v0 = (i0 < NBUCK) ? btot[i0] : 0;
    int v1 = (i1 < NBUCK) ? btot[i1] : 0;
    int s = v0 + v1;
    int lane = t & 63, w = t >> 6;
    int incl = s;
    for (int o = 1; o < 64; o <<= 1) {
        int v = __shfl_up(incl, o);
        if (lane >= o) incl += v;
    }
    __shared__ int wsum[4];
    if (lane == 63) wsum[w] = incl;
    __syncthreads();
    int wbase = 0;
#pragma unroll
    for (int i = 0; i < 4; ++i) if (i < w) wbase += wsum[i];
    int excl = wbase + incl - s;
    if (i0 <= NBUCK) bbase[i0] = excl;
    if (i1 <= NBUCK) bbase[i1] = excl + v0;
}

// ---------------------------------------------------------------------------
// fusedB: blocks [0,521) = p1b scatter (overlaps qkv);
// blocks [521, 521+3125) = qkv single-tile LDS-staged, XP=132,
// B-frags = one coalesced 1KB wave-load each from fragment-packed wt.
// ---------------------------------------------------------------------------
#define XP 132   // padded k-stride (ushort) for LDS x tiles

__global__ __launch_bounds__(256) void fusedB_kernel(
    const float* __restrict__ x,
    const unsigned short* __restrict__ wt_hi,
    const unsigned short* __restrict__ wt_lo,
    const float* __restrict__ bq, const float* __restrict__ bk,
    const float* __restrict__ bv,
    float* __restrict__ Qo, unsigned int* __restrict__ KVb,
    const int* __restrict__ ei, const float* __restrict__ ea,
    const int* __restrict__ hist, const int* __restrict__ bbase,
    int2* __restrict__ staging)
{
    __shared__ __align__(16) char smem[2 * 32 * XP * 2];   // 16896 B union

    const int t = threadIdx.x;

    if (blockIdx.x < NB_P1) {
        // ---- p1b body (first: overlaps qkv compute) ----
        int* lr = (int*)smem;
        const int pb = blockIdx.x;
        for (int b = t; b < NBUCK; b += 256)
            lr[b] = hist[pb * NBUCK + b] + bbase[b];
        __syncthreads();

        const int e0 = pb * P1_TILE;
#pragma unroll
        for (int j = 0; j < 12; ++j) {
            int e = e0 + j * 256 + t;
            if (e < EE) {
                int s = ei[e];
                int d = ei[EE + e];
                int pos = atomicAdd(&lr[d >> BSHIFT], 1);
                staging[pos] = make_int2(s | ((d & 255) << 17), __float_as_int(ea[e]));
            }
        }
        return;
    }

    // ---- qkv body ----
    unsigned short* xhi = (unsigned short*)smem;             // 32*XP ushorts
    unsigned short* xlo = (unsigned short*)(smem + 32 * XP * 2);

    const int qb   = blockIdx.x - NB_P1;     // 0..3124
    const int wave = t >> 6;
    const int lane = t & 63;
    const int nb   = qb * 32;                // 3125 * 32 = 100000 exact

    // stage x tile 32x128 fp32 -> hi/lo bf16 in LDS (16 floats/thread)
    {
        const int row = t >> 3;          // 0..31
        const int c   = t & 7;           // 16-float chunk
        const float* xr = x + (size_t)(nb + row) * IND + c * 16;
        float4 a0 = *(const float4*)(xr);
        float4 a1 = *(const float4*)(xr + 4);
        float4 a2 = *(const float4*)(xr + 8);
        float4 a3 = *(const float4*)(xr + 12);
        float vs[16] = { a0.x, a0.y, a0.z, a0.w, a1.x, a1.y, a1.z, a1.w,
                         a2.x, a2.y, a2.z, a2.w, a3.x, a3.y, a3.z, a3.w };
        short8 h0, h1, l0, l1;
#pragma unroll
        for (int j = 0; j < 8; ++j) {
            unsigned short hb = bf16_rne(vs[j]);
            float hf = __uint_as_float((unsigned int)hb << 16);
            h0[j] = (short)hb;
            l0[j] = (short)bf16_rne(vs[j] - hf);
        }
#pragma unroll
        for (int j = 0; j < 8; ++j) {
            unsigned short hb = bf16_rne(vs[8 + j]);
            float hf = __uint_as_float((unsigned int)hb << 16);
            h1[j] = (short)hb;
            l1[j] = (short)bf16_rne(vs[8 + j] - hf);
        }
        int o0 = row * XP + c * 16;
        *(short8*)&xhi[o0]     = h0;
        *(short8*)&xhi[o0 + 8] = h1;
        *(short8*)&xlo[o0]     = l0;
        *(short8*)&xlo[o0 + 8] = l1;
    }
    __syncthreads();

    f32x4 acc[2][3];
#pragma unroll
    for (int rt = 0; rt < 2; ++rt)
#pragma unroll
        for (int ct = 0; ct < 3; ++ct)
            acc[rt][ct] = (f32x4){0.f, 0.f, 0.f, 0.f};

#pragma unroll
    for (int kt = 0; kt < 4; ++kt) {
        // stream B-fragments for this kt: ONE coalesced 1KB load each
        short8 bh[3], bl[3];
#pragma unroll
        for (int ct = 0; ct < 3; ++ct) {
            int ctg = wave * 3 + ct;             // global col-tile 0..11
            int a = ((ctg * 4) + kt) * 512 + lane * 8;
            bh[ct] = *(const short8*)&wt_hi[a];
            bl[ct] = *(const short8*)&wt_lo[a];
        }
        // A-fragments from LDS (4 x ds_read_b128)
        short8 ah[2], al[2];
#pragma unroll
        for (int rt = 0; rt < 2; ++rt) {
            int o2 = (rt * 16 + (lane & 15)) * XP + kt * 32 + (lane >> 4) * 8;
            ah[rt] = *(const short8*)&xhi[o2];
            al[rt] = *(const short8*)&xlo[o2];
        }
#pragma unroll
        for (int rt = 0; rt < 2; ++rt) {
#pragma unroll
            for (int ct = 0; ct < 3; ++ct) {
                acc[rt][ct] = __builtin_amdgcn_mfma_f32_16x16x32_bf16(
                    ah[rt], bh[ct], acc[rt][ct], 0, 0, 0);
                acc[rt][ct] = __builtin_amdgcn_mfma_f32_16x16x32_bf16(
                    ah[rt], bl[ct], acc[rt][ct], 0, 0, 0);
                acc[rt][ct] = __builtin_amdgcn_mfma_f32_16x16x32_bf16(
                    al[rt], bh[ct], acc[rt][ct], 0, 0, 0);
            }
        }
    }

    // epilogue: bias + store. Q fp32; K -> hi ushort, V -> lo ushort
    const int wcol0 = wave * 48;
#pragma unroll
    for (int ct = 0; ct < 3; ++ct) {
        int colbase = wcol0 + ct * 16;
        int m  = colbase >> 6;                 // wave-uniform: 0=Q,1=K,2=V
        int lc = (colbase & 63) + (lane & 15);
        const float* bp = (m == 0) ? bq : (m == 1) ? bk : bv;
        float bias = bp[lc];
#pragma unroll
        for (int rt = 0; rt < 2; ++rt) {
#pragma unroll
            for (int reg = 0; reg < 4; ++reg) {
                int node = nb + rt * 16 + (lane >> 4) * 4 + reg;
                float val = acc[rt][ct][reg] + bias;
                size_t idx = (size_t)node * D64 + lc;
                if (m == 0) {
                    Qo[idx] = val;
                } else {
                    // little-endian: ushort[0]=lo(V), ushort[1]=hi(K)
                    ((unsigned short*)KVb)[idx * 2 + (m == 1 ? 1 : 0)] = bf16_rne(val);
                }
            }
        }
    }
}

// ---------------------------------------------------------------------------
// p2: one block per bucket. Count per-node into LDS; 256-wide scan seeded
// at bbase[bucket] -> writes off[]; place records via LDS cursors.
// ---------------------------------------------------------------------------
__global__ __launch_bounds__(256) void p2_kernel(const int2* __restrict__ staging,
                                                 const int* __restrict__ bbase,
                                                 int* __restrict__ off,
                                                 int2* __restrict__ epack)
{
    const int bucket = blockIdx.x;
    const int t      = threadIdx.x;
    const int n0     = bucket << BSHIFT;
    const int sb     = bbase[bucket];
    const int se     = bbase[bucket + 1];

    __shared__ int lcnt[256];
    __shared__ int lcur[256];
    __shared__ int wsum[4];
    lcnt[t] = 0;
    __syncthreads();

    for (int r = sb + t; r < se; r += 256)
        atomicAdd(&lcnt[(staging[r].x >> 17) & 255], 1);
    __syncthreads();

    int cnt  = lcnt[t];
    int lane = t & 63, w = t >> 6;
    int incl = cnt;
    for (int o = 1; o < 64; o <<= 1) {
        int v = __shfl_up(incl, o);
        if (lane >= o) incl += v;
    }
    if (lane == 63) wsum[w] = incl;
    __syncthreads();
    int wbase = 0;
#pragma unroll
    for (int i = 0; i < 4; ++i) if (i < w) wbase += wsum[i];
    int ov = sb + wbase + incl - cnt;     // exclusive offset for node n0+t

    int node = n0 + t;
    if (node <= NN) off[node] = ov;
    lcur[t] = ov;
    __syncthreads();

    for (int r = sb + t; r < se; r += 256) {
        int2 rec = staging[r];
        int dl = (rec.x >> 17) & 255;
        int pos = atomicAdd(&lcur[dl], 1);
        epack[pos] = make_int2(rec.x & 0x1FFFF, rec.y);
    }
}

// ---------------------------------------------------------------------------
// Attention: one wave per dst node; lane = es*8 + h (8 edges x 8 heads).
// Unguarded full steps + one predicated tail; 32-bit byte addressing.
// ---------------------------------------------------------------------------
__global__ __launch_bounds__(256) void attn_kernel(
    const float* __restrict__ Q, const unsigned int* __restrict__ KVb,
    const int* __restrict__ off, const int2* __restrict__ epack,
    const float* __restrict__ We, const float* __restrict__ be,
    float* __restrict__ out)
{
    const int lane = threadIdx.x & 63;
    const int node = blockIdx.x * 4 + (threadIdx.x >> 6);   // grid exact: < NN

    const int h  = lane & 7;    // head owned by this lane
    const int es = lane >> 3;   // edge slot 0..7

    // ---- hoist: fold Q, We, be, 1/sqrt(8) into per-d score coefficients ----
    float wq[8], bq[8];
    {
        const float4* qp = (const float4*)&Q[(size_t)node * D64 + h * 8];
        float4 q0 = qp[0], q1 = qp[1];
        const float4* wp = (const float4*)&We[h * 8];
        float4 w0 = wp[0], w1 = wp[1];
        const float4* bp = (const float4*)&be[h * 8];
        float4 b0 = bp[0], b1 = bp[1];
        const float rs = 0.35355339059327373f;
        float qs[8] = { q0.x, q0.y, q0.z, q0.w, q1.x, q1.y, q1.z, q1.w };
        float ws[8] = { w0.x, w0.y, w0.z, w0.w, w1.x, w1.y, w1.z, w1.w };
        float bs[8] = { b0.x, b0.y, b0.z, b0.w, b1.x, b1.y, b1.z, b1.w };
#pragma unroll
        for (int d = 0; d < 8; ++d) {
            float qr = qs[d] * rs;
            wq[d] = ws[d] * qr;
            bq[d] = bs[d] * qr;
        }
    }

    const int i0 = off[node];
    const int i1 = off[node + 1];

    float acc[8];
#pragma unroll
    for (int d = 0; d < 8; ++d) acc[d] = 0.f;
    float z = 0.f;

    int i = i0;
    // ---- full steps: no predication anywhere ----
#pragma unroll 2
    for (; i + 8 <= i1; i += 8) {
        int2 rec = epack[i + es];
        unsigned int bo = ((unsigned int)rec.x << 6) + (h << 3);
        float attr = __int_as_float(rec.y);

        uint4 wA = *(const uint4*)(KVb + bo);
        uint4 wB = *(const uint4*)(KVb + bo + 4);
        unsigned int wv[8] = { wA.x, wA.y, wA.z, wA.w, wB.x, wB.y, wB.z, wB.w };

        float tt = 0.f;
#pragma unroll
        for (int d = 0; d < 8; ++d) {
            float s  = fmaf(attr, wq[d], bq[d]);
            float kf = __uint_as_float(wv[d] & 0xFFFF0000u);
            tt = fmaf(kf, s, tt);
        }
        tt = fminf(fmaxf(tt, -5.f), 5.f);
        float sc = __expf(tt);

#pragma unroll
        for (int d = 0; d < 8; ++d) {
            float vf = __uint_as_float(wv[d] << 16);
            acc[d] = fmaf(vf, sc, acc[d]);
        }
        z += sc;
    }

    // ---- tail: one predicated step covers remaining 0..7 edges ----
    if (i < i1) {
        int  idx   = i + es;
        bool valid = idx < i1;
        int2 rec   = epack[valid ? idx : i0];
        unsigned int bo = ((unsigned int)rec.x << 6) + (h << 3);
        float attr = __int_as_float(rec.y);

        uint4 wA = *(const uint4*)(KVb + bo);
        uint4 wB = *(const uint4*)(KVb + bo + 4);
        unsigned int wv[8] = { wA.x, wA.y, wA.z, wA.w, wB.x, wB.y, wB.z, wB.w };

        float tt = 0.f;
#pragma unroll
        for (int d = 0; d < 8; ++d) {
            float s  = fmaf(attr, wq[d], bq[d]);
            float kf = __uint_as_float(wv[d] & 0xFFFF0000u);
            tt = fmaf(kf, s, tt);
        }
        tt = fminf(fmaxf(tt, -5.f), 5.f);
        float sc = __expf(tt);
        sc = valid ? sc : 0.f;

#pragma unroll
        for (int d = 0; d < 8; ++d) {
            float vf = __uint_as_float(wv[d] << 16);
            acc[d] = fmaf(vf, sc, acc[d]);
        }
        z += sc;
    }

    // ---- butterfly reduce across edge slots (lane bits 3..5) ----
#pragma unroll
    for (int m = 8; m <= 32; m <<= 1) {
#pragma unroll
        for (int d = 0; d < 8; ++d) acc[d] += __shfl_xor(acc[d], m);
        z += __shfl_xor(z, m);
    }

    // ---- lane writes out[node][h*8 + es] = acc[es] / (z + eps) ----
    float val = acc[0];
#pragma unroll
    for (int j = 1; j < 8; ++j)
        val = (es == j) ? acc[j] : val;

    out[(size_t)node * D64 + h * 8 + es] = val / (z + 1e-6f);
}

// ---------------------------------------------------------------------------
// Host launcher
// ---------------------------------------------------------------------------
static inline size_t align256(size_t v) { return (v + 255) & ~(size_t)255; }

extern "C" void kernel_launch(void* const* d_in, const int* in_sizes, int n_in,
                              void* d_out, int out_size, void* d_ws, size_t ws_size,
                              hipStream_t stream)
{
    const float* x  = (const float*)d_in[0];
    const float* ea = (const float*)d_in[1];
    const int*   ei = (const int*)  d_in[2];   // [2][EE]: row0=src, row1=dst
    const float* Wq = (const float*)d_in[3];
    const float* bq = (const float*)d_in[4];
    const float* Wk = (const float*)d_in[5];
    const float* bk = (const float*)d_in[6];
    const float* We = (const float*)d_in[7];
    const float* be = (const float*)d_in[8];
    const float* Wv = (const float*)d_in[9];
    const float* bv = (const float*)d_in[10];
    float* out = (float*)d_out;

    char* ws = (char*)d_ws;
    size_t o = 0;
    float*          Q       = (float*)(ws + o);          o += align256((size_t)NN * D64 * 4);
    unsigned int*   KVb     = (unsigned int*)(ws + o);   o += align256((size_t)NN * D64 * 4);
    int*            off     = (int*)(ws + o);            o += align256((size_t)(NN + 1) * 4);
    unsigned short* wt_hi   = (unsigned short*)(ws + o); o += align256((size_t)192 * 128 * 2);
    unsigned short* wt_lo   = (unsigned short*)(ws + o); o += align256((size_t)192 * 128 * 2);
    int*            hist    = (int*)(ws + o);            o += align256((size_t)NB_P1 * NBUCK * 4);
    int*            btot    = (int*)(ws + o);            o += align256((size_t)NBUCK * 4);
    int*            bbase   = (int*)(ws + o);            o += align256((size_t)(NBUCK + 1) * 4);
    int2*           staging = (int2*)(ws + o);           o += align256((size_t)EE * 8);
    int2*           epack   = (int2*)(ws + o);           o += align256((size_t)EE * 8);
    (void)ws_size; (void)out_size; (void)in_sizes; (void)n_in;

    fusedA_kernel<<<WT_BLOCKS + NB_P1, 256, 0, stream>>>(Wq, Wk, Wv, wt_hi, wt_lo, ei, hist);
    hscanA_kernel<<<NBUCK, 256, 0, stream>>>(hist, btot);
    bscan_kernel<<<1, 256, 0, stream>>>(btot, bbase);
    fusedB_kernel<<<NB_P1 + QKV_BLOCKS, 256, 0, stream>>>(x, wt_hi, wt_lo, bq, bk, bv,
                                                          Q, KVb, ei, ea, hist, bbase, staging);
    p2_kernel<<<NBUCK, 256, 0, stream>>>(staging, bbase, off, epack);
    attn_kernel<<<NN / 4, 256, 0, stream>>>(Q, KVb, off, epack, We, be, out);
}

// Round 19
// 142.146 us; speedup vs baseline: 1.3129x; 1.0192x over previous
//
#include <hip/hip_runtime.h>
#include <math.h>

#define NN 100000
#define EE 1600000
#define IND 128
#define D64 64    // HEADS*OUT_DIM

#define BSHIFT 8          // bucket = dst >> 8 (256 nodes per bucket)
#define NBUCK 391         // ceil(NN / 256)
#define P1_TILE 3072
#define NB_P1 521         // ceil(EE / P1_TILE)

#define QKV_BLOCKS 3125   // NN / 32
#define WT_BLOCKS 96

typedef __attribute__((ext_vector_type(8))) short  short8;
typedef __attribute__((ext_vector_type(4))) float  f32x4;

__device__ __forceinline__ unsigned short bf16_rne(float v) {
    unsigned int u = __float_as_uint(v);
    return (unsigned short)((u + 0x7FFFu + ((u >> 16) & 1u)) >> 16);
}

// ---------------------------------------------------------------------------
// fusedA: blocks [0,96) = wtrans -> FRAGMENT-PACKED wt layout:
//   wt[((ct*4+kt)*64 + lane)*8 + j] = W[kt*32+(lane>>4)*8+j][ct*16+(lane&15)]
// so each MFMA B-fragment is one coalesced 1KB wave-load.
// blocks [96, 96+521) = p1a histogram.
// ---------------------------------------------------------------------------
__global__ __launch_bounds__(256) void fusedA_kernel(
    const float* __restrict__ Wq, const float* __restrict__ Wk,
    const float* __restrict__ Wv,
    unsigned short* __restrict__ wt_hi, unsigned short* __restrict__ wt_lo,
    const int* __restrict__ ei, int* __restrict__ hist)
{
    __shared__ int lh[NBUCK];
    const int t = threadIdx.x;

    if (blockIdx.x < WT_BLOCKS) {
        // ---- wtrans body (fragment-packed) ----
        int idx = blockIdx.x * 256 + t;           // 0..24575 == 192*128
        int j    = idx & 7;
        int lane = (idx >> 3) & 63;
        int ktct = idx >> 9;                      // 0..47
        int kt   = ktct & 3;
        int ct   = ktct >> 2;                     // 0..11
        int col  = ct * 16 + (lane & 15);
        int k    = kt * 32 + (lane >> 4) * 8 + j;
        const float* W = (col < 64) ? Wq : (col < 128) ? Wk : Wv;
        float v = W[(size_t)k * D64 + (col & 63)];
        unsigned short h = bf16_rne(v);
        float hf = __uint_as_float((unsigned int)h << 16);
        unsigned short l = bf16_rne(v - hf);
        wt_hi[idx] = h;
        wt_lo[idx] = l;
        return;
    }

    // ---- p1a body ----
    const int pb = blockIdx.x - WT_BLOCKS;
    for (int b = t; b < NBUCK; b += 256) lh[b] = 0;
    __syncthreads();

    const int e0 = pb * P1_TILE;
#pragma unroll
    for (int j = 0; j < 12; ++j) {
        int e = e0 + j * 256 + t;
        if (e < EE) {
            int d = ei[EE + e];
            atomicAdd(&lh[d >> BSHIFT], 1);
        }
    }
    __syncthreads();
    for (int b = t; b < NBUCK; b += 256)
        hist[pb * NBUCK + b] = lh[b];
}

// ---------------------------------------------------------------------------
// hscanA: block b = bucket b. Unseeded exclusive scan of hist column
// (in place) + emits btot[b].
// ---------------------------------------------------------------------------
__global__ __launch_bounds__(256) void hscanA_kernel(int* __restrict__ hist,
                                                     int* __restrict__ btot)
{
    const int b = blockIdx.x;
    const int t = threadIdx.x;
    int L[3]; int s = 0;
#pragma unroll
    for (int j = 0; j < 3; ++j) {
        int blk = t * 3 + j;
        L[j] = (blk < NB_P1) ? hist[blk * NBUCK + b] : 0;
        s += L[j];
    }
    int lane = t & 63, w = t >> 6;
    int incl = s;
    for (int o = 1; o < 64; o <<= 1) {
        int v = __shfl_up(incl, o);
        if (lane >= o) incl += v;
    }
    __shared__ int wsum[4];
    if (lane == 63) wsum[w] = incl;
    __syncthreads();
    int wbase = 0;
#pragma unroll
    for (int i = 0; i < 4; ++i) if (i < w) wbase += wsum[i];
    int run = wbase + incl - s;          // unseeded exclusive offset
#pragma unroll
    for (int j = 0; j < 3; ++j) {
        int blk = t * 3 + j;
        if (blk < NB_P1) hist[blk * NBUCK + b] = run;
        run += L[j];
    }
    if (t == 0) btot[b] = wsum[0] + wsum[1] + wsum[2] + wsum[3];
}

// ---------------------------------------------------------------------------
// bscan: exclusive scan of 391 bucket totals -> bbase[0..391].
// ---------------------------------------------------------------------------
__global__ __launch_bounds__(256) void bscan_kernel(const int* __restrict__ btot,
                                                    int* __restrict__ bbase)
{
    const int t = threadIdx.x;
    int i0 = 2 * t, i1 = 2 * t + 1;
    int v0 = (i0 < NBUCK) ? btot[i0] : 0;
    int v1 = (i1 < NBUCK) ? btot[i1] : 0;
    int s = v0 + v1;
    int lane = t & 63, w = t >> 6;
    int incl = s;
    for (int o = 1; o < 64; o <<= 1) {
        int v = __shfl_up(incl, o);
        if (lane >= o) incl += v;
    }
    __shared__ int wsum[4];
    if (lane == 63) wsum[w] = incl;
    __syncthreads();
    int wbase = 0;
#pragma unroll
    for (int i = 0; i < 4; ++i) if (i < w) wbase += wsum[i];
    int excl = wbase + incl - s;
    if (i0 <= NBUCK) bbase[i0] = excl;
    if (i1 <= NBUCK) bbase[i1] = excl + v0;
}

// ---------------------------------------------------------------------------
// fusedB: blocks [0,521) = p1b scatter (overlaps qkv);
// blocks [521, 521+3125) = qkv single-tile LDS-staged, XP=132,
// B-frags = one coalesced 1KB wave-load each from fragment-packed wt.
// Q stored BF16 (halves Q traffic both sides).
// ---------------------------------------------------------------------------
#define XP 132   // padded k-stride (ushort) for LDS x tiles

__global__ __launch_bounds__(256) void fusedB_kernel(
    const float* __restrict__ x,
    const unsigned short* __restrict__ wt_hi,
    const unsigned short* __restrict__ wt_lo,
    const float* __restrict__ bq, const float* __restrict__ bk,
    const float* __restrict__ bv,
    unsigned short* __restrict__ Qb, unsigned int* __restrict__ KVb,
    const int* __restrict__ ei, const float* __restrict__ ea,
    const int* __restrict__ hist, const int* __restrict__ bbase,
    int2* __restrict__ staging)
{
    __shared__ __align__(16) char smem[2 * 32 * XP * 2];   // 16896 B union

    const int t = threadIdx.x;

    if (blockIdx.x < NB_P1) {
        // ---- p1b body (first: overlaps qkv compute) ----
        int* lr = (int*)smem;
        const int pb = blockIdx.x;
        for (int b = t; b < NBUCK; b += 256)
            lr[b] = hist[pb * NBUCK + b] + bbase[b];
        __syncthreads();

        const int e0 = pb * P1_TILE;
#pragma unroll
        for (int j = 0; j < 12; ++j) {
            int e = e0 + j * 256 + t;
            if (e < EE) {
                int s = ei[e];
                int d = ei[EE + e];
                int pos = atomicAdd(&lr[d >> BSHIFT], 1);
                staging[pos] = make_int2(s | ((d & 255) << 17), __float_as_int(ea[e]));
            }
        }
        return;
    }

    // ---- qkv body ----
    unsigned short* xhi = (unsigned short*)smem;             // 32*XP ushorts
    unsigned short* xlo = (unsigned short*)(smem + 32 * XP * 2);

    const int qb   = blockIdx.x - NB_P1;     // 0..3124
    const int wave = t >> 6;
    const int lane = t & 63;
    const int nb   = qb * 32;                // 3125 * 32 = 100000 exact

    // stage x tile 32x128 fp32 -> hi/lo bf16 in LDS (16 floats/thread)
    {
        const int row = t >> 3;          // 0..31
        const int c   = t & 7;           // 16-float chunk
        const float* xr = x + (size_t)(nb + row) * IND + c * 16;
        float4 a0 = *(const float4*)(xr);
        float4 a1 = *(const float4*)(xr + 4);
        float4 a2 = *(const float4*)(xr + 8);
        float4 a3 = *(const float4*)(xr + 12);
        float vs[16] = { a0.x, a0.y, a0.z, a0.w, a1.x, a1.y, a1.z, a1.w,
                         a2.x, a2.y, a2.z, a2.w, a3.x, a3.y, a3.z, a3.w };
        short8 h0, h1, l0, l1;
#pragma unroll
        for (int j = 0; j < 8; ++j) {
            unsigned short hb = bf16_rne(vs[j]);
            float hf = __uint_as_float((unsigned int)hb << 16);
            h0[j] = (short)hb;
            l0[j] = (short)bf16_rne(vs[j] - hf);
        }
#pragma unroll
        for (int j = 0; j < 8; ++j) {
            unsigned short hb = bf16_rne(vs[8 + j]);
            float hf = __uint_as_float((unsigned int)hb << 16);
            h1[j] = (short)hb;
            l1[j] = (short)bf16_rne(vs[8 + j] - hf);
        }
        int o0 = row * XP + c * 16;
        *(short8*)&xhi[o0]     = h0;
        *(short8*)&xhi[o0 + 8] = h1;
        *(short8*)&xlo[o0]     = l0;
        *(short8*)&xlo[o0 + 8] = l1;
    }
    __syncthreads();

    f32x4 acc[2][3];
#pragma unroll
    for (int rt = 0; rt < 2; ++rt)
#pragma unroll
        for (int ct = 0; ct < 3; ++ct)
            acc[rt][ct] = (f32x4){0.f, 0.f, 0.f, 0.f};

#pragma unroll
    for (int kt = 0; kt < 4; ++kt) {
        // stream B-fragments for this kt: ONE coalesced 1KB load each
        short8 bh[3], bl[3];
#pragma unroll
        for (int ct = 0; ct < 3; ++ct) {
            int ctg = wave * 3 + ct;             // global col-tile 0..11
            int a = ((ctg * 4) + kt) * 512 + lane * 8;
            bh[ct] = *(const short8*)&wt_hi[a];
            bl[ct] = *(const short8*)&wt_lo[a];
        }
        // A-fragments from LDS (4 x ds_read_b128)
        short8 ah[2], al[2];
#pragma unroll
        for (int rt = 0; rt < 2; ++rt) {
            int o2 = (rt * 16 + (lane & 15)) * XP + kt * 32 + (lane >> 4) * 8;
            ah[rt] = *(const short8*)&xhi[o2];
            al[rt] = *(const short8*)&xlo[o2];
        }
#pragma unroll
        for (int rt = 0; rt < 2; ++rt) {
#pragma unroll
            for (int ct = 0; ct < 3; ++ct) {
                acc[rt][ct] = __builtin_amdgcn_mfma_f32_16x16x32_bf16(
                    ah[rt], bh[ct], acc[rt][ct], 0, 0, 0);
                acc[rt][ct] = __builtin_amdgcn_mfma_f32_16x16x32_bf16(
                    ah[rt], bl[ct], acc[rt][ct], 0, 0, 0);
                acc[rt][ct] = __builtin_amdgcn_mfma_f32_16x16x32_bf16(
                    al[rt], bh[ct], acc[rt][ct], 0, 0, 0);
            }
        }
    }

    // epilogue: bias + store. Q -> bf16; K -> hi ushort, V -> lo ushort
    const int wcol0 = wave * 48;
#pragma unroll
    for (int ct = 0; ct < 3; ++ct) {
        int colbase = wcol0 + ct * 16;
        int m  = colbase >> 6;                 // wave-uniform: 0=Q,1=K,2=V
        int lc = (colbase & 63) + (lane & 15);
        const float* bp = (m == 0) ? bq : (m == 1) ? bk : bv;
        float bias = bp[lc];
#pragma unroll
        for (int rt = 0; rt < 2; ++rt) {
#pragma unroll
            for (int reg = 0; reg < 4; ++reg) {
                int node = nb + rt * 16 + (lane >> 4) * 4 + reg;
                float val = acc[rt][ct][reg] + bias;
                size_t idx = (size_t)node * D64 + lc;
                if (m == 0) {
                    Qb[idx] = bf16_rne(val);
                } else {
                    // little-endian: ushort[0]=lo(V), ushort[1]=hi(K)
                    ((unsigned short*)KVb)[idx * 2 + (m == 1 ? 1 : 0)] = bf16_rne(val);
                }
            }
        }
    }
}

// ---------------------------------------------------------------------------
// p2: one block per bucket. Count per-node into LDS; 256-wide scan seeded
// at bbase[bucket] -> writes off[]; place records via LDS cursors.
// ---------------------------------------------------------------------------
__global__ __launch_bounds__(256) void p2_kernel(const int2* __restrict__ staging,
                                                 const int* __restrict__ bbase,
                                                 int* __restrict__ off,
                                                 int2* __restrict__ epack)
{
    const int bucket = blockIdx.x;
    const int t      = threadIdx.x;
    const int n0     = bucket << BSHIFT;
    const int sb     = bbase[bucket];
    const int se     = bbase[bucket + 1];

    __shared__ int lcnt[256];
    __shared__ int lcur[256];
    __shared__ int wsum[4];
    lcnt[t] = 0;
    __syncthreads();

    for (int r = sb + t; r < se; r += 256)
        atomicAdd(&lcnt[(staging[r].x >> 17) & 255], 1);
    __syncthreads();

    int cnt  = lcnt[t];
    int lane = t & 63, w = t >> 6;
    int incl = cnt;
    for (int o = 1; o < 64; o <<= 1) {
        int v = __shfl_up(incl, o);
        if (lane >= o) incl += v;
    }
    if (lane == 63) wsum[w] = incl;
    __syncthreads();
    int wbase = 0;
#pragma unroll
    for (int i = 0; i < 4; ++i) if (i < w) wbase += wsum[i];
    int ov = sb + wbase + incl - cnt;     // exclusive offset for node n0+t

    int node = n0 + t;
    if (node <= NN) off[node] = ov;
    lcur[t] = ov;
    __syncthreads();

    for (int r = sb + t; r < se; r += 256) {
        int2 rec = staging[r];
        int dl = (rec.x >> 17) & 255;
        int pos = atomicAdd(&lcur[dl], 1);
        epack[pos] = make_int2(rec.x & 0x1FFFF, rec.y);
    }
}

// ---------------------------------------------------------------------------
// Attention: one wave per dst node; lane = es*8 + h (8 edges x 8 heads).
// Q read as bf16x8 (one uint4 per lane). Unguarded full steps + one
// predicated tail; 32-bit byte addressing.
// ---------------------------------------------------------------------------
__global__ __launch_bounds__(256) void attn_kernel(
    const unsigned short* __restrict__ Qb, const unsigned int* __restrict__ KVb,
    const int* __restrict__ off, const int2* __restrict__ epack,
    const float* __restrict__ We, const float* __restrict__ be,
    float* __restrict__ out)
{
    const int lane = threadIdx.x & 63;
    const int node = blockIdx.x * 4 + (threadIdx.x >> 6);   // grid exact: < NN

    const int h  = lane & 7;    // head owned by this lane
    const int es = lane >> 3;   // edge slot 0..7

    // ---- hoist: fold Q, We, be, 1/sqrt(8) into per-d score coefficients ----
    float wq[8], bq[8];
    {
        uint4 qr = *(const uint4*)&Qb[(size_t)node * D64 + h * 8];
        unsigned int qu[4] = { qr.x, qr.y, qr.z, qr.w };
        const float4* wp = (const float4*)&We[h * 8];
        float4 w0 = wp[0], w1 = wp[1];
        const float4* bp = (const float4*)&be[h * 8];
        float4 b0 = bp[0], b1 = bp[1];
        const float rs = 0.35355339059327373f;
        float qs[8];
#pragma unroll
        for (int p = 0; p < 4; ++p) {
            qs[2 * p]     = __uint_as_float(qu[p] << 16);
            qs[2 * p + 1] = __uint_as_float(qu[p] & 0xFFFF0000u);
        }
        float ws[8] = { w0.x, w0.y, w0.z, w0.w, w1.x, w1.y, w1.z, w1.w };
        float bs[8] = { b0.x, b0.y, b0.z, b0.w, b1.x, b1.y, b1.z, b1.w };
#pragma unroll
        for (int d = 0; d < 8; ++d) {
            float qrr = qs[d] * rs;
            wq[d] = ws[d] * qrr;
            bq[d] = bs[d] * qrr;
        }
    }

    const int i0 = off[node];
    const int i1 = off[node + 1];

    float acc[8];
#pragma unroll
    for (int d = 0; d < 8; ++d) acc[d] = 0.f;
    float z = 0.f;

    int i = i0;
    // ---- full steps: no predication anywhere ----
#pragma unroll 2
    for (; i + 8 <= i1; i += 8) {
        int2 rec = epack[i + es];
        unsigned int bo = ((unsigned int)rec.x << 6) + (h << 3);
        float attr = __int_as_float(rec.y);

        uint4 wA = *(const uint4*)(KVb + bo);
        uint4 wB = *(const uint4*)(KVb + bo + 4);
        unsigned int wv[8] = { wA.x, wA.y, wA.z, wA.w, wB.x, wB.y, wB.z, wB.w };

        float tt = 0.f;
#pragma unroll
        for (int d = 0; d < 8; ++d) {
            float s  = fmaf(attr, wq[d], bq[d]);
            float kf = __uint_as_float(wv[d] & 0xFFFF0000u);
            tt = fmaf(kf, s, tt);
        }
        tt = fminf(fmaxf(tt, -5.f), 5.f);
        float sc = __expf(tt);

#pragma unroll
        for (int d = 0; d < 8; ++d) {
            float vf = __uint_as_float(wv[d] << 16);
            acc[d] = fmaf(vf, sc, acc[d]);
        }
        z += sc;
    }

    // ---- tail: one predicated step covers remaining 0..7 edges ----
    if (i < i1) {
        int  idx   = i + es;
        bool valid = idx < i1;
        int2 rec   = epack[valid ? idx : i0];
        unsigned int bo = ((unsigned int)rec.x << 6) + (h << 3);
        float attr = __int_as_float(rec.y);

        uint4 wA = *(const uint4*)(KVb + bo);
        uint4 wB = *(const uint4*)(KVb + bo + 4);
        unsigned int wv[8] = { wA.x, wA.y, wA.z, wA.w, wB.x, wB.y, wB.z, wB.w };

        float tt = 0.f;
#pragma unroll
        for (int d = 0; d < 8; ++d) {
            float s  = fmaf(attr, wq[d], bq[d]);
            float kf = __uint_as_float(wv[d] & 0xFFFF0000u);
            tt = fmaf(kf, s, tt);
        }
        tt = fminf(fmaxf(tt, -5.f), 5.f);
        float sc = __expf(tt);
        sc = valid ? sc : 0.f;

#pragma unroll
        for (int d = 0; d < 8; ++d) {
            float vf = __uint_as_float(wv[d] << 16);
            acc[d] = fmaf(vf, sc, acc[d]);
        }
        z += sc;
    }

    // ---- butterfly reduce across edge slots (lane bits 3..5) ----
#pragma unroll
    for (int m = 8; m <= 32; m <<= 1) {
#pragma unroll
        for (int d = 0; d < 8; ++d) acc[d] += __shfl_xor(acc[d], m);
        z += __shfl_xor(z, m);
    }

    // ---- lane writes out[node][h*8 + es] = acc[es] / (z + eps) ----
    float val = acc[0];
#pragma unroll
    for (int j = 1; j < 8; ++j)
        val = (es == j) ? acc[j] : val;

    out[(size_t)node * D64 + h * 8 + es] = val / (z + 1e-6f);
}

// ---------------------------------------------------------------------------
// Host launcher
// ---------------------------------------------------------------------------
static inline size_t align256(size_t v) { return (v + 255) & ~(size_t)255; }

extern "C" void kernel_launch(void* const* d_in, const int* in_sizes, int n_in,
                              void* d_out, int out_size, void* d_ws, size_t ws_size,
                              hipStream_t stream)
{
    const float* x  = (const float*)d_in[0];
    const float* ea = (const float*)d_in[1];
    const int*   ei = (const int*)  d_in[2];   // [2][EE]: row0=src, row1=dst
    const float* Wq = (const float*)d_in[3];
    const float* bq = (const float*)d_in[4];
    const float* Wk = (const float*)d_in[5];
    const float* bk = (const float*)d_in[6];
    const float* We = (const float*)d_in[7];
    const float* be = (const float*)d_in[8];
    const float* Wv = (const float*)d_in[9];
    const float* bv = (const float*)d_in[10];
    float* out = (float*)d_out;

    char* ws = (char*)d_ws;
    size_t o = 0;
    unsigned short* Qb      = (unsigned short*)(ws + o); o += align256((size_t)NN * D64 * 2);
    unsigned int*   KVb     = (unsigned int*)(ws + o);   o += align256((size_t)NN * D64 * 4);
    int*            off     = (int*)(ws + o);            o += align256((size_t)(NN + 1) * 4);
    unsigned short* wt_hi   = (unsigned short*)(ws + o); o += align256((size_t)192 * 128 * 2);
    unsigned short* wt_lo   = (unsigned short*)(ws + o); o += align256((size_t)192 * 128 * 2);
    int*            hist    = (int*)(ws + o);            o += align256((size_t)NB_P1 * NBUCK * 4);
    int*            btot    = (int*)(ws + o);            o += align256((size_t)NBUCK * 4);
    int*            bbase   = (int*)(ws + o);            o += align256((size_t)(NBUCK + 1) * 4);
    int2*           staging = (int2*)(ws + o);           o += align256((size_t)EE * 8);
    int2*           epack   = (int2*)(ws + o);           o += align256((size_t)EE * 8);
    (void)ws_size; (void)out_size; (void)in_sizes; (void)n_in;

    fusedA_kernel<<<WT_BLOCKS + NB_P1, 256, 0, stream>>>(Wq, Wk, Wv, wt_hi, wt_lo, ei, hist);
    hscanA_kernel<<<NBUCK, 256, 0, stream>>>(hist, btot);
    bscan_kernel<<<1, 256, 0, stream>>>(btot, bbase);
    fusedB_kernel<<<NB_P1 + QKV_BLOCKS, 256, 0, stream>>>(x, wt_hi, wt_lo, bq, bk, bv,
                                                          Qb, KVb, ei, ea, hist, bbase, staging);
    p2_kernel<<<NBUCK, 256, 0, stream>>>(staging, bbase, off, epack);
    attn_kernel<<<NN / 4, 256, 0, stream>>>(Qb, KVb, off, epack, We, be, out);
}